// Round 17
// baseline (598.947 us; speedup 1.0000x reference)
//
#include <hip/hip_runtime.h>
#include <stdint.h>

#define Bn 32
#define Nn 1723
#define Cn 512
#define Hn 256
#define NK 54     // K-steps of 32 (K padded to 1728)

typedef __bf16 bf16x8 __attribute__((ext_vector_type(8)));
typedef float f32x4 __attribute__((ext_vector_type(4)));
typedef unsigned short u16;

__device__ __forceinline__ u16 f2b(float f){
  union{float f; uint32_t i;} c; c.f=f; uint32_t u=c.i;
  u += 0x7fffu + ((u>>16)&1u);
  return (u16)(u>>16);
}
__device__ __forceinline__ bf16x8 ld8(const u16* p){
  union{ uint4 u; bf16x8 b; } c;
  c.u = *reinterpret_cast<const uint4*>(p);
  return c.b;
}
__device__ __forceinline__ f32x4 mfma16(bf16x8 a, bf16x8 b, f32x4 c){
  return __builtin_amdgcn_mfma_f32_16x16x32_bf16(a,b,c,0,0,0);
}

// ---- kernel 0: weights -> bf16 MFMA-fragment-major (validated R5) ----
__global__ __launch_bounds__(256) void k_prep(
    const float* __restrict__ W1, const float* __restrict__ Wc, const float* __restrict__ W2,
    u16* __restrict__ W1f, u16* __restrict__ WcTf, u16* __restrict__ W2f)
{
  const int t = blockIdx.x*256 + threadIdx.x;
  const int lane = t & 63, unit = t >> 6;
  const int lr = lane & 15, lh = lane >> 4;
  const float* src; u16* dst; int K, tile, kk; bool tr = false;
  if (unit < 256){ tile = unit>>4; kk = unit&15; src = W1; dst = W1f; K = 512; }
  else if (unit < 384){ int u = unit-256; tile = u>>3; kk = u&7; src = Wc; dst = WcTf; K = 256; tr = true; }
  else { int u = unit-384; tile = u>>3; kk = u&7; src = W2; dst = W2f; K = 256; }
  const int row = tile*16 + lr;
  const int k0 = kk*32 + lh*8;
  union{u16 s[8]; uint4 u;} o;
  #pragma unroll
  for (int j=0;j<8;++j){
    float v = tr ? src[(size_t)(k0+j)*256 + row] : src[(size_t)row*K + k0 + j];
    o.s[j] = f2b(v);
  }
  *reinterpret_cast<uint4*>(dst + (size_t)(tile*(K/32)+kk)*512 + lane*8) = o.u;
}

// ---------------- stage A (validated R15; phantom vertices ZEROED in supT) ----------------
__global__ __launch_bounds__(256) void k_stageA(
    const float* __restrict__ x, const float* __restrict__ prw, const float* __restrict__ prb,
    const u16* __restrict__ W1f, const float* __restrict__ b1,
    const float* __restrict__ n1w, const float* __restrict__ n1b,
    const u16* __restrict__ WcTf, u16* __restrict__ supT)
{
  __shared__ u16 t1[32*512];
  __shared__ float ps[2][32], pq[2][32];
  u16* const t2 = t1;
  const int b = blockIdx.y;
  const int m0 = blockIdx.x*32;
  const int tid = threadIdx.x;
  const int w = tid>>6, l = tid&63, lr = l&15, lh = l>>4;
  const int wm = w>>1, wn = w&1;

  float pw[8], pb[8];
  #pragma unroll
  for (int j=0;j<8;++j){ pw[j]=prw[l*8+j]; pb[j]=prb[l*8+j]; }
  #pragma unroll
  for (int rr=0; rr<8; ++rr){
    const int rloc = w*8+rr;
    int rg = m0 + rloc; rg = rg < Nn ? rg : Nn-1;
    const float* src = x + ((size_t)b*Nn + rg)*Cn + l*8;
    float4 c0 = *reinterpret_cast<const float4*>(src);
    float4 c1 = *reinterpret_cast<const float4*>(src+4);
    float v[8] = {c0.x,c0.y,c0.z,c0.w,c1.x,c1.y,c1.z,c1.w};
    float s=0.f, q=0.f;
    #pragma unroll
    for (int j=0;j<8;++j){ s+=v[j]; q+=v[j]*v[j]; }
    #pragma unroll
    for (int m=1;m<64;m<<=1){ s += __shfl_xor(s,m); q += __shfl_xor(q,m); }
    const float mean = s*(1.f/Cn);
    const float rstd = rsqrtf(fmaxf(q*(1.f/Cn) - mean*mean, 0.f) + 1e-12f);
    union{uint4 u; u16 s[8];} ov;
    #pragma unroll
    for (int j=0;j<8;++j){
      float t = (v[j]-mean)*rstd*pw[j] + pb[j];
      ov.s[j] = f2b(fmaxf(t,0.f));
    }
    const int idx = (rloc*512 + l*8) ^ ((rloc&7)<<3);
    *reinterpret_cast<uint4*>(&t1[idx]) = ov.u;
  }
  __syncthreads();

  f32x4 acc[8];
  #pragma unroll
  for (int i=0;i<8;++i) acc[i] = f32x4{0.f,0.f,0.f,0.f};
  const int arow = wm*16 + lr;
  const int aswz = (arow&7)<<3;
  for (int kk=0; kk<16; ++kk){
    bf16x8 a = ld8(&t1[(arow*512 + kk*32 + lh*8) ^ aswz]);
    #pragma unroll
    for (int nt=0; nt<8; ++nt){
      bf16x8 bb = ld8(W1f + (size_t)(((wn*8+nt)*16 + kk))*512 + l*8);
      acc[nt] = mfma16(a, bb, acc[nt]);
    }
  }

  float sum[4]={0,0,0,0}, sq[4]={0,0,0,0};
  #pragma unroll
  for (int nt=0; nt<8; ++nt){
    const float bias = b1[wn*128+nt*16+lr];
    #pragma unroll
    for (int r=0;r<4;++r){
      float vv = acc[nt][r] + bias;
      acc[nt][r] = vv; sum[r]+=vv; sq[r]+=vv*vv;
    }
  }
  #pragma unroll
  for (int m=1;m<16;m<<=1){
    #pragma unroll
    for (int r=0;r<4;++r){ sum[r]+=__shfl_xor(sum[r],m); sq[r]+=__shfl_xor(sq[r],m); }
  }
  if (lr==0){
    #pragma unroll
    for (int r=0;r<4;++r){
      const int row = wm*16 + lh*4 + r;
      ps[wn][row]=sum[r]; pq[wn][row]=sq[r];
    }
  }
  __syncthreads();
  float mean[4], rstd[4];
  #pragma unroll
  for (int r=0;r<4;++r){
    const int row = wm*16 + lh*4 + r;
    const float S = ps[0][row]+ps[1][row];
    const float Q = pq[0][row]+pq[1][row];
    const float mu = S*(1.f/Hn);
    mean[r] = mu;
    rstd[r] = rsqrtf(fmaxf(Q*(1.f/Hn) - mu*mu, 0.f) + 1e-12f);
  }
  #pragma unroll
  for (int nt=0; nt<8; ++nt){
    const int col = wn*128+nt*16+lr;
    const float nw = n1w[col], nb = n1b[col];
    #pragma unroll
    for (int r=0;r<4;++r){
      const int row = wm*16 + lh*4 + r;
      float t = (acc[nt][r]-mean[r])*rstd[r]*nw + nb;
      t2[(row*256 + col) ^ ((row&7)<<3)] = f2b(fmaxf(t,0.f));
    }
  }
  __syncthreads();

  f32x4 acc2[8];
  #pragma unroll
  for (int i=0;i<8;++i) acc2[i] = f32x4{0.f,0.f,0.f,0.f};
  for (int kk=0; kk<8; ++kk){
    bf16x8 a = ld8(&t2[(arow*256 + kk*32 + lh*8) ^ aswz]);
    #pragma unroll
    for (int nt=0; nt<8; ++nt){
      bf16x8 bb = ld8(WcTf + (size_t)(((wn*8+nt)*8 + kk))*512 + l*8);
      acc2[nt] = mfma16(a, bb, acc2[nt]);
    }
  }

  const int off512 = (wm*2 + (lh>>1))*128 + lr*8 + (lh&1)*4;
  const int vbase = m0 + wm*16 + lh*4;
  #pragma unroll
  for (int nt=0; nt<8; ++nt){
    const int htile = wn*8 + nt;
    const size_t base = ((size_t)(b*16 + htile)*NK + blockIdx.x)*512 + off512;
    ushort4 o;
    o.x = (vbase+0 < Nn) ? f2b(acc2[nt][0]) : (u16)0;
    o.y = (vbase+1 < Nn) ? f2b(acc2[nt][1]) : (u16)0;
    o.z = (vbase+2 < Nn) ? f2b(acc2[nt][2]) : (u16)0;
    o.w = (vbase+3 < Nn) ? f2b(acc2[nt][3]) : (u16)0;
    *reinterpret_cast<ushort4*>(supT + base) = o;
  }
}

// ---------------- adjT: adj f32 row-major -> adjF bf16 MFMA-fragment-major (VECTORIZED) ----------------
// grid 3456 = 32 b x 108 mtiles. float4 coalesced reads (block reads a contiguous 110KB
// adj region) -> LDS bf16 tile -> 54 contiguous 1KB fragment writes.
// adjF frag (b, mtile, kk): u16[lane*8+j] = adj[m0+(lane&15)][kk*32+(lane>>4)*8+j]; phantom -> 0.
__global__ __launch_bounds__(256) void k_adjT(
    const float* __restrict__ adj, u16* __restrict__ adjF)
{
  __shared__ u16 tile[16*1736];    // 54.25 KB; row stride 1736 u16 (2-way-free reads)
  const int bid = blockIdx.x;
  const int b = bid / 108;
  const int mtile = bid % 108;
  const int m0 = mtile*16;
  const int tid = threadIdx.x;
  const float* adjb = adj + (size_t)b*Nn*Nn;

  #pragma unroll 4
  for (int row=0; row<16; ++row){
    const int grow = m0 + row;
    const bool rok = grow < Nn;
    const float* rp = adjb + (size_t)(rok ? grow : Nn-1)*Nn;
    #pragma unroll
    for (int it=0; it<2; ++it){
      const int col = tid*4 + it*1024;
      if (col < 1728){
        ushort4 ov;
        if (rok && col+3 < Nn){
          float4 v = *reinterpret_cast<const float4*>(rp + col);
          ov.x = f2b(v.x); ov.y = f2b(v.y); ov.z = f2b(v.z); ov.w = f2b(v.w);
        } else {
          float e0 = (rok && col+0 < Nn) ? rp[col+0] : 0.f;
          float e1 = (rok && col+1 < Nn) ? rp[col+1] : 0.f;
          float e2 = (rok && col+2 < Nn) ? rp[col+2] : 0.f;
          float e3 = (rok && col+3 < Nn) ? rp[col+3] : 0.f;
          ov.x = f2b(e0); ov.y = f2b(e1); ov.z = f2b(e2); ov.w = f2b(e3);
        }
        *reinterpret_cast<ushort4*>(&tile[row*1736 + col]) = ov;
      }
    }
  }
  __syncthreads();

  const int l = tid & 63, w = tid >> 6, lr = l & 15, lh = l >> 4;
  const size_t fb = (size_t)bid * NK;      // bid == b*108 + mtile
  for (int kk = w; kk < NK; kk += 4){
    uint4 v = *reinterpret_cast<const uint4*>(&tile[lr*1736 + kk*32 + lh*8]);
    *reinterpret_cast<uint4*>(adjF + (fb + kk)*512 + l*8) = v;
  }
}

// ---------------- stage B: BARRIER-FREE all-register GEMM1 + LN + GEMM2 (R12-B2 mode) ----------------
// grid 1728 = 8 xcd x (4 b x 54 tiles of 32 rows). 4 waves; wave w: GEMM1 cols w*64..+63.
// K-loop: 6 contiguous 1KB ld8 streams (2 adjF + 4 supT) + 8 MFMAs per kk. No LDS, no barriers.
__global__ __launch_bounds__(256) void k_stageB(
    const u16* __restrict__ adjF, const u16* __restrict__ supT,
    const float* __restrict__ cb, const float* __restrict__ n2w, const float* __restrict__ n2b,
    const u16* __restrict__ W2f, const float* __restrict__ bl2,
    const float* __restrict__ x, float* __restrict__ out)
{
  __shared__ u16 t3[32*256];       // 16 KB
  __shared__ float ps[4][32], pq[4][32];
  const int bid = blockIdx.x;
  const int xcd = bid & 7, idx = bid >> 3;
  const int b = xcd*4 + (idx & 3);          // 4 consecutive b per XCD (supT slice L2-resident)
  const int t32 = idx >> 2;                 // 0..53
  const int m0 = t32 * 32;
  const int tid = threadIdx.x, w = tid>>6, l = tid&63, lr = l&15, lh = l>>4;

  const u16* af0 = adjF + (size_t)(b*108 + t32*2    )*NK*512 + l*8;
  const u16* af1 = adjF + (size_t)(b*108 + t32*2 + 1)*NK*512 + l*8;
  const u16* sf  = supT + (size_t)(b*16 + 4*w)*NK*512 + l*8;

  f32x4 acc1[2][4];
  #pragma unroll
  for (int i=0;i<2;++i)
    #pragma unroll
    for (int j=0;j<4;++j) acc1[i][j] = f32x4{0.f,0.f,0.f,0.f};

  #pragma unroll 3
  for (int kk=0; kk<NK; ++kk){
    bf16x8 a0 = ld8(af0 + (size_t)kk*512);
    bf16x8 a1 = ld8(af1 + (size_t)kk*512);
    bf16x8 b0 = ld8(sf + (size_t)(0*NK + kk)*512);
    bf16x8 b1 = ld8(sf + (size_t)(1*NK + kk)*512);
    bf16x8 b2 = ld8(sf + (size_t)(2*NK + kk)*512);
    bf16x8 b3 = ld8(sf + (size_t)(3*NK + kk)*512);
    acc1[0][0] = mfma16(a0, b0, acc1[0][0]);
    acc1[0][1] = mfma16(a0, b1, acc1[0][1]);
    acc1[0][2] = mfma16(a0, b2, acc1[0][2]);
    acc1[0][3] = mfma16(a0, b3, acc1[0][3]);
    acc1[1][0] = mfma16(a1, b0, acc1[1][0]);
    acc1[1][1] = mfma16(a1, b1, acc1[1][1]);
    acc1[1][2] = mfma16(a1, b2, acc1[1][2]);
    acc1[1][3] = mfma16(a1, b3, acc1[1][3]);
  }

  // ---- +conv_b, LN(256) across waves, relu -> t3 (validated epilogue) ----
  float sum[2][4], sq[2][4];
  #pragma unroll
  for (int mt=0;mt<2;++mt)
    #pragma unroll
    for (int r=0;r<4;++r){ sum[mt][r]=0.f; sq[mt][r]=0.f; }
  float biasv[4];
  #pragma unroll
  for (int nt=0;nt<4;++nt) biasv[nt] = cb[w*64+nt*16+lr];
  #pragma unroll
  for (int mt=0;mt<2;++mt)
    #pragma unroll
    for (int nt=0;nt<4;++nt)
      #pragma unroll
      for (int r=0;r<4;++r){
        float vv = acc1[mt][nt][r] + biasv[nt];
        acc1[mt][nt][r] = vv; sum[mt][r]+=vv; sq[mt][r]+=vv*vv;
      }
  #pragma unroll
  for (int m=1;m<16;m<<=1){
    #pragma unroll
    for (int mt=0;mt<2;++mt)
      #pragma unroll
      for (int r=0;r<4;++r){ sum[mt][r]+=__shfl_xor(sum[mt][r],m); sq[mt][r]+=__shfl_xor(sq[mt][r],m); }
  }
  if (lr==0){
    #pragma unroll
    for (int mt=0;mt<2;++mt)
      #pragma unroll
      for (int r=0;r<4;++r){
        const int row = mt*16+lh*4+r;
        ps[w][row]=sum[mt][r]; pq[w][row]=sq[mt][r];
      }
  }
  __syncthreads();
  float meanv[2][4], rstdv[2][4];
  #pragma unroll
  for (int mt=0;mt<2;++mt)
    #pragma unroll
    for (int r=0;r<4;++r){
      const int row = mt*16+lh*4+r;
      const float S = ps[0][row]+ps[1][row]+ps[2][row]+ps[3][row];
      const float Q = pq[0][row]+pq[1][row]+pq[2][row]+pq[3][row];
      const float mu = S*(1.f/Hn);
      meanv[mt][r] = mu;
      rstdv[mt][r] = rsqrtf(fmaxf(Q*(1.f/Hn)-mu*mu, 0.f) + 1e-12f);
    }
  #pragma unroll
  for (int nt=0;nt<4;++nt){
    const int c2 = w*64+nt*16+lr;
    const float nw = n2w[c2], nb = n2b[c2];
    #pragma unroll
    for (int mt=0;mt<2;++mt)
      #pragma unroll
      for (int r=0;r<4;++r){
        const int row = mt*16+lh*4+r;
        float t = (acc1[mt][nt][r]-meanv[mt][r])*rstdv[mt][r]*nw + nb;
        t3[(row*256+c2) ^ ((row&7)<<3)] = f2b(fmaxf(t,0.f));
      }
  }
  __syncthreads();

  // ---- GEMM2 (two 64-col halves): y[32x512] = t3 @ lin2_W^T (K=256) + bias + x ----
  #pragma unroll
  for (int h=0; h<2; ++h){
    f32x4 acc2[2][4];
    #pragma unroll
    for (int i=0;i<2;++i)
      #pragma unroll
      for (int j=0;j<4;++j) acc2[i][j] = f32x4{0.f,0.f,0.f,0.f};
    for (int kk=0;kk<8;++kk){
      bf16x8 a[2];
      #pragma unroll
      for (int mt=0;mt<2;++mt){
        const int row = mt*16+lr;
        a[mt] = ld8(&t3[(row*256 + kk*32 + lh*8) ^ ((row&7)<<3)]);
      }
      #pragma unroll
      for (int nt=0;nt<4;++nt){
        bf16x8 bb = ld8(W2f + (size_t)(((w*8 + h*4 + nt)*8) + kk)*512 + l*8);
        #pragma unroll
        for (int mt=0;mt<2;++mt) acc2[mt][nt] = mfma16(a[mt], bb, acc2[mt][nt]);
      }
    }
    #pragma unroll
    for (int nt=0;nt<4;++nt){
      const int c2 = w*128 + h*64 + nt*16 + lr;
      const float bias = bl2[c2];
      #pragma unroll
      for (int mt=0;mt<2;++mt){
        #pragma unroll
        for (int r=0;r<4;++r){
          const int mg = m0 + mt*16 + lh*4 + r;
          if (mg < Nn){
            const size_t off = ((size_t)b*Nn + mg)*Cn + c2;
            out[off] = acc2[mt][nt][r] + bias + x[off];
          }
        }
      }
    }
  }
}

extern "C" void kernel_launch(void* const* d_in, const int* in_sizes, int n_in,
                              void* d_out, int out_size, void* d_ws, size_t ws_size,
                              hipStream_t stream){
  const float* x    = (const float*)d_in[0];
  const float* adj  = (const float*)d_in[1];
  const float* prw  = (const float*)d_in[2];
  const float* prb  = (const float*)d_in[3];
  const float* W1   = (const float*)d_in[4];
  const float* b1   = (const float*)d_in[5];
  const float* n1w  = (const float*)d_in[6];
  const float* n1b  = (const float*)d_in[7];
  const float* Wc   = (const float*)d_in[8];
  const float* cbv  = (const float*)d_in[9];
  const float* n2w  = (const float*)d_in[10];
  const float* n2b  = (const float*)d_in[11];
  const float* W2   = (const float*)d_in[12];
  const float* bl2  = (const float*)d_in[13];

  u16* ws    = (u16*)d_ws;
  u16* W1f   = ws;                                   // 131072 u16
  u16* WcTf  = ws + 131072;                          // 65536
  u16* W2f   = ws + 131072 + 65536;                  // 131072
  u16* supT  = ws + 327680;                          // 32*16*54*512  = 14,155,776 u16 (~27 MiB)
  u16* adjF  = supT + (size_t)32*16*54*512;          // 32*108*54*512 = 95,551,488 u16 (~182 MiB)
  // total ws use ~210 MiB (d_ws ~1.45 GB per harness poison-fill WRITE_SIZE)

  k_prep<<<dim3(160), dim3(256), 0, stream>>>(W1, Wc, W2, W1f, WcTf, W2f);
  k_stageA<<<dim3(NK,Bn), dim3(256), 0, stream>>>(x, prw, prb, W1f, b1, n1w, n1b, WcTf, supT);
  k_adjT<<<dim3(3456), dim3(256), 0, stream>>>(adj, adjF);
  k_stageB<<<dim3(1728), dim3(256), 0, stream>>>(adjF, supT, cbv, n2w, n2b, W2f, bl2, x, (float*)d_out);
}

// Round 18
// 539.818 us; speedup vs baseline: 1.1095x; 1.1095x over previous
//
#include <hip/hip_runtime.h>
#include <stdint.h>

#define Bn 32
#define Nn 1723
#define Cn 512
#define Hn 256
#define NK 54     // K-steps of 32 (K padded to 1728)

typedef __bf16 bf16x8 __attribute__((ext_vector_type(8)));
typedef float f32x4 __attribute__((ext_vector_type(4)));
typedef unsigned short u16;

__device__ __forceinline__ u16 f2b(float f){
  union{float f; uint32_t i;} c; c.f=f; uint32_t u=c.i;
  u += 0x7fffu + ((u>>16)&1u);
  return (u16)(u>>16);
}
__device__ __forceinline__ bf16x8 ld8(const u16* p){
  union{ uint4 u; bf16x8 b; } c;
  c.u = *reinterpret_cast<const uint4*>(p);
  return c.b;
}
__device__ __forceinline__ f32x4 mfma16(bf16x8 a, bf16x8 b, f32x4 c){
  return __builtin_amdgcn_mfma_f32_16x16x32_bf16(a,b,c,0,0,0);
}

// ---- kernel 0: weights -> bf16 MFMA-fragment-major (validated R5) ----
__global__ __launch_bounds__(256) void k_prep(
    const float* __restrict__ W1, const float* __restrict__ Wc, const float* __restrict__ W2,
    u16* __restrict__ W1f, u16* __restrict__ WcTf, u16* __restrict__ W2f)
{
  const int t = blockIdx.x*256 + threadIdx.x;
  const int lane = t & 63, unit = t >> 6;
  const int lr = lane & 15, lh = lane >> 4;
  const float* src; u16* dst; int K, tile, kk; bool tr = false;
  if (unit < 256){ tile = unit>>4; kk = unit&15; src = W1; dst = W1f; K = 512; }
  else if (unit < 384){ int u = unit-256; tile = u>>3; kk = u&7; src = Wc; dst = WcTf; K = 256; tr = true; }
  else { int u = unit-384; tile = u>>3; kk = u&7; src = W2; dst = W2f; K = 256; }
  const int row = tile*16 + lr;
  const int k0 = kk*32 + lh*8;
  union{u16 s[8]; uint4 u;} o;
  #pragma unroll
  for (int j=0;j<8;++j){
    float v = tr ? src[(size_t)(k0+j)*256 + row] : src[(size_t)row*K + k0 + j];
    o.s[j] = f2b(v);
  }
  *reinterpret_cast<uint4*>(dst + (size_t)(tile*(K/32)+kk)*512 + lane*8) = o.u;
}

// ---------------- stage A (validated R15/R16; phantom vertices ZEROED in supT) ----------------
__global__ __launch_bounds__(256) void k_stageA(
    const float* __restrict__ x, const float* __restrict__ prw, const float* __restrict__ prb,
    const u16* __restrict__ W1f, const float* __restrict__ b1,
    const float* __restrict__ n1w, const float* __restrict__ n1b,
    const u16* __restrict__ WcTf, u16* __restrict__ supT)
{
  __shared__ u16 t1[32*512];
  __shared__ float ps[2][32], pq[2][32];
  u16* const t2 = t1;
  const int b = blockIdx.y;
  const int m0 = blockIdx.x*32;
  const int tid = threadIdx.x;
  const int w = tid>>6, l = tid&63, lr = l&15, lh = l>>4;
  const int wm = w>>1, wn = w&1;

  float pw[8], pb[8];
  #pragma unroll
  for (int j=0;j<8;++j){ pw[j]=prw[l*8+j]; pb[j]=prb[l*8+j]; }
  #pragma unroll
  for (int rr=0; rr<8; ++rr){
    const int rloc = w*8+rr;
    int rg = m0 + rloc; rg = rg < Nn ? rg : Nn-1;
    const float* src = x + ((size_t)b*Nn + rg)*Cn + l*8;
    float4 c0 = *reinterpret_cast<const float4*>(src);
    float4 c1 = *reinterpret_cast<const float4*>(src+4);
    float v[8] = {c0.x,c0.y,c0.z,c0.w,c1.x,c1.y,c1.z,c1.w};
    float s=0.f, q=0.f;
    #pragma unroll
    for (int j=0;j<8;++j){ s+=v[j]; q+=v[j]*v[j]; }
    #pragma unroll
    for (int m=1;m<64;m<<=1){ s += __shfl_xor(s,m); q += __shfl_xor(q,m); }
    const float mean = s*(1.f/Cn);
    const float rstd = rsqrtf(fmaxf(q*(1.f/Cn) - mean*mean, 0.f) + 1e-12f);
    union{uint4 u; u16 s[8];} ov;
    #pragma unroll
    for (int j=0;j<8;++j){
      float t = (v[j]-mean)*rstd*pw[j] + pb[j];
      ov.s[j] = f2b(fmaxf(t,0.f));
    }
    const int idx = (rloc*512 + l*8) ^ ((rloc&7)<<3);
    *reinterpret_cast<uint4*>(&t1[idx]) = ov.u;
  }
  __syncthreads();

  f32x4 acc[8];
  #pragma unroll
  for (int i=0;i<8;++i) acc[i] = f32x4{0.f,0.f,0.f,0.f};
  const int arow = wm*16 + lr;
  const int aswz = (arow&7)<<3;
  for (int kk=0; kk<16; ++kk){
    bf16x8 a = ld8(&t1[(arow*512 + kk*32 + lh*8) ^ aswz]);
    #pragma unroll
    for (int nt=0; nt<8; ++nt){
      bf16x8 bb = ld8(W1f + (size_t)(((wn*8+nt)*16 + kk))*512 + l*8);
      acc[nt] = mfma16(a, bb, acc[nt]);
    }
  }

  float sum[4]={0,0,0,0}, sq[4]={0,0,0,0};
  #pragma unroll
  for (int nt=0; nt<8; ++nt){
    const float bias = b1[wn*128+nt*16+lr];
    #pragma unroll
    for (int r=0;r<4;++r){
      float vv = acc[nt][r] + bias;
      acc[nt][r] = vv; sum[r]+=vv; sq[r]+=vv*vv;
    }
  }
  #pragma unroll
  for (int m=1;m<16;m<<=1){
    #pragma unroll
    for (int r=0;r<4;++r){ sum[r]+=__shfl_xor(sum[r],m); sq[r]+=__shfl_xor(sq[r],m); }
  }
  if (lr==0){
    #pragma unroll
    for (int r=0;r<4;++r){
      const int row = wm*16 + lh*4 + r;
      ps[wn][row]=sum[r]; pq[wn][row]=sq[r];
    }
  }
  __syncthreads();
  float mean[4], rstd[4];
  #pragma unroll
  for (int r=0;r<4;++r){
    const int row = wm*16 + lh*4 + r;
    const float S = ps[0][row]+ps[1][row];
    const float Q = pq[0][row]+pq[1][row];
    const float mu = S*(1.f/Hn);
    mean[r] = mu;
    rstd[r] = rsqrtf(fmaxf(Q*(1.f/Hn) - mu*mu, 0.f) + 1e-12f);
  }
  #pragma unroll
  for (int nt=0; nt<8; ++nt){
    const int col = wn*128+nt*16+lr;
    const float nw = n1w[col], nb = n1b[col];
    #pragma unroll
    for (int r=0;r<4;++r){
      const int row = wm*16 + lh*4 + r;
      float t = (acc[nt][r]-mean[r])*rstd[r]*nw + nb;
      t2[(row*256 + col) ^ ((row&7)<<3)] = f2b(fmaxf(t,0.f));
    }
  }
  __syncthreads();

  f32x4 acc2[8];
  #pragma unroll
  for (int i=0;i<8;++i) acc2[i] = f32x4{0.f,0.f,0.f,0.f};
  for (int kk=0; kk<8; ++kk){
    bf16x8 a = ld8(&t2[(arow*256 + kk*32 + lh*8) ^ aswz]);
    #pragma unroll
    for (int nt=0; nt<8; ++nt){
      bf16x8 bb = ld8(WcTf + (size_t)(((wn*8+nt)*8 + kk))*512 + l*8);
      acc2[nt] = mfma16(a, bb, acc2[nt]);
    }
  }

  const int off512 = (wm*2 + (lh>>1))*128 + lr*8 + (lh&1)*4;
  const int vbase = m0 + wm*16 + lh*4;
  #pragma unroll
  for (int nt=0; nt<8; ++nt){
    const int htile = wn*8 + nt;
    const size_t base = ((size_t)(b*16 + htile)*NK + blockIdx.x)*512 + off512;
    ushort4 o;
    o.x = (vbase+0 < Nn) ? f2b(acc2[nt][0]) : (u16)0;
    o.y = (vbase+1 < Nn) ? f2b(acc2[nt][1]) : (u16)0;
    o.z = (vbase+2 < Nn) ? f2b(acc2[nt][2]) : (u16)0;
    o.w = (vbase+3 < Nn) ? f2b(acc2[nt][3]) : (u16)0;
    *reinterpret_cast<ushort4*>(supT + base) = o;
  }
}

// ---------------- adjT: adj f32 row-major -> adjF bf16 MFMA-fragment-major (validated R16) ----------------
__global__ __launch_bounds__(256) void k_adjT(
    const float* __restrict__ adj, u16* __restrict__ adjF)
{
  __shared__ u16 tile[16*1736];    // 54.25 KB; row stride 1736 u16
  const int bid = blockIdx.x;
  const int b = bid / 108;
  const int mtile = bid % 108;
  const int m0 = mtile*16;
  const int tid = threadIdx.x;
  const float* adjb = adj + (size_t)b*Nn*Nn;

  #pragma unroll 4
  for (int row=0; row<16; ++row){
    const int grow = m0 + row;
    const bool rok = grow < Nn;
    const float* rp = adjb + (size_t)(rok ? grow : Nn-1)*Nn;
    #pragma unroll
    for (int it=0; it<2; ++it){
      const int col = tid*4 + it*1024;
      if (col < 1728){
        ushort4 ov;
        if (rok && col+3 < Nn){
          float4 v = *reinterpret_cast<const float4*>(rp + col);
          ov.x = f2b(v.x); ov.y = f2b(v.y); ov.z = f2b(v.z); ov.w = f2b(v.w);
        } else {
          float e0 = (rok && col+0 < Nn) ? rp[col+0] : 0.f;
          float e1 = (rok && col+1 < Nn) ? rp[col+1] : 0.f;
          float e2 = (rok && col+2 < Nn) ? rp[col+2] : 0.f;
          float e3 = (rok && col+3 < Nn) ? rp[col+3] : 0.f;
          ov.x = f2b(e0); ov.y = f2b(e1); ov.z = f2b(e2); ov.w = f2b(e3);
        }
        *reinterpret_cast<ushort4*>(&tile[row*1736 + col]) = ov;
      }
    }
  }
  __syncthreads();

  const int l = tid & 63, w = tid >> 6, lr = l & 15, lh = l >> 4;
  const size_t fb = (size_t)bid * NK;      // bid == b*108 + mtile
  #pragma unroll
  for (int i=0; i<14; ++i){
    const int kk = w + i*4;
    if (kk < NK){
      uint4 v = *reinterpret_cast<const uint4*>(&tile[lr*1736 + kk*32 + lh*8]);
      *reinterpret_cast<uint4*>(adjF + (fb + kk)*512 + l*8) = v;
    }
  }
}

// ---------------- stage B: register GEMM1 with EXPLICIT 3-DEEP rotating prefetch ----------------
// grid 1728 = 8 xcd x (4 b x 54 tiles of 32 rows). 4 waves; wave w: GEMM1 cols w*64..+63.
// Sets S0/S1/S2 (6 bf16x8 each, statically indexed): consume Si(kk), reload Si(kk+3).
// Reload->consume distance = 3 kk; compiler emits counted vmcnt; no LDS/barriers in loop.
__global__ __launch_bounds__(256) void k_stageB(
    const u16* __restrict__ adjF, const u16* __restrict__ supT,
    const float* __restrict__ cb, const float* __restrict__ n2w, const float* __restrict__ n2b,
    const u16* __restrict__ W2f, const float* __restrict__ bl2,
    const float* __restrict__ x, float* __restrict__ out)
{
  __shared__ u16 t3[32*256];       // 16 KB
  __shared__ float ps[4][32], pq[4][32];
  const int bid = blockIdx.x;
  const int xcd = bid & 7, idx = bid >> 3;
  const int b = xcd*4 + (idx & 3);          // 4 consecutive b per XCD (supT slice L2-resident)
  const int t32 = idx >> 2;                 // 0..53
  const int m0 = t32 * 32;
  const int tid = threadIdx.x, w = tid>>6, l = tid&63, lr = l&15, lh = l>>4;

  const u16* af0 = adjF + (size_t)(b*108 + t32*2    )*NK*512 + l*8;
  const u16* af1 = adjF + (size_t)(b*108 + t32*2 + 1)*NK*512 + l*8;
  const u16* sf  = supT + (size_t)(b*16 + 4*w)*NK*512 + l*8;

  f32x4 acc1[2][4];
  #pragma unroll
  for (int i=0;i<2;++i)
    #pragma unroll
    for (int j=0;j<4;++j) acc1[i][j] = f32x4{0.f,0.f,0.f,0.f};

  typedef struct { bf16x8 a0,a1,b0,b1,b2,b3; } kset;
  kset S0, S1, S2;

  #define LOADSET(S, kk) do{                                 \
    S.a0 = ld8(af0 + (size_t)(kk)*512);                      \
    S.a1 = ld8(af1 + (size_t)(kk)*512);                      \
    S.b0 = ld8(sf + (size_t)(0*NK + (kk))*512);              \
    S.b1 = ld8(sf + (size_t)(1*NK + (kk))*512);              \
    S.b2 = ld8(sf + (size_t)(2*NK + (kk))*512);              \
    S.b3 = ld8(sf + (size_t)(3*NK + (kk))*512);              \
  }while(0)

  #define MFMASET(S) do{                                     \
    acc1[0][0] = mfma16(S.a0, S.b0, acc1[0][0]);             \
    acc1[0][1] = mfma16(S.a0, S.b1, acc1[0][1]);             \
    acc1[0][2] = mfma16(S.a0, S.b2, acc1[0][2]);             \
    acc1[0][3] = mfma16(S.a0, S.b3, acc1[0][3]);             \
    acc1[1][0] = mfma16(S.a1, S.b0, acc1[1][0]);             \
    acc1[1][1] = mfma16(S.a1, S.b1, acc1[1][1]);             \
    acc1[1][2] = mfma16(S.a1, S.b2, acc1[1][2]);             \
    acc1[1][3] = mfma16(S.a1, S.b3, acc1[1][3]);             \
  }while(0)

  LOADSET(S0, 0); LOADSET(S1, 1); LOADSET(S2, 2);
  #pragma unroll 1
  for (int p=0; p<17; ++p){
    const int kk = 3*p;
    MFMASET(S0);  LOADSET(S0, kk+3);
    MFMASET(S1);  LOADSET(S1, kk+4);
    MFMASET(S2);  LOADSET(S2, kk+5);
  }
  MFMASET(S0);   // kk=51
  MFMASET(S1);   // kk=52
  MFMASET(S2);   // kk=53
  #undef LOADSET
  #undef MFMASET

  // ---- +conv_b, LN(256) across waves, relu -> t3 (validated epilogue) ----
  float sum[2][4], sq[2][4];
  #pragma unroll
  for (int mt=0;mt<2;++mt)
    #pragma unroll
    for (int r=0;r<4;++r){ sum[mt][r]=0.f; sq[mt][r]=0.f; }
  float biasv[4];
  #pragma unroll
  for (int nt=0;nt<4;++nt) biasv[nt] = cb[w*64+nt*16+lr];
  #pragma unroll
  for (int mt=0;mt<2;++mt)
    #pragma unroll
    for (int nt=0;nt<4;++nt)
      #pragma unroll
      for (int r=0;r<4;++r){
        float vv = acc1[mt][nt][r] + biasv[nt];
        acc1[mt][nt][r] = vv; sum[mt][r]+=vv; sq[mt][r]+=vv*vv;
      }
  #pragma unroll
  for (int m=1;m<16;m<<=1){
    #pragma unroll
    for (int mt=0;mt<2;++mt)
      #pragma unroll
      for (int r=0;r<4;++r){ sum[mt][r]+=__shfl_xor(sum[mt][r],m); sq[mt][r]+=__shfl_xor(sq[mt][r],m); }
  }
  if (lr==0){
    #pragma unroll
    for (int mt=0;mt<2;++mt)
      #pragma unroll
      for (int r=0;r<4;++r){
        const int row = mt*16+lh*4+r;
        ps[w][row]=sum[mt][r]; pq[w][row]=sq[mt][r];
      }
  }
  __syncthreads();
  float meanv[2][4], rstdv[2][4];
  #pragma unroll
  for (int mt=0;mt<2;++mt)
    #pragma unroll
    for (int r=0;r<4;++r){
      const int row = mt*16+lh*4+r;
      const float S = ps[0][row]+ps[1][row]+ps[2][row]+ps[3][row];
      const float Q = pq[0][row]+pq[1][row]+pq[2][row]+pq[3][row];
      const float mu = S*(1.f/Hn);
      meanv[mt][r] = mu;
      rstdv[mt][r] = rsqrtf(fmaxf(Q*(1.f/Hn)-mu*mu, 0.f) + 1e-12f);
    }
  #pragma unroll
  for (int nt=0;nt<4;++nt){
    const int c2 = w*64+nt*16+lr;
    const float nw = n2w[c2], nb = n2b[c2];
    #pragma unroll
    for (int mt=0;mt<2;++mt)
      #pragma unroll
      for (int r=0;r<4;++r){
        const int row = mt*16+lh*4+r;
        float t = (acc1[mt][nt][r]-meanv[mt][r])*rstdv[mt][r]*nw + nb;
        t3[(row*256+c2) ^ ((row&7)<<3)] = f2b(fmaxf(t,0.f));
      }
  }
  __syncthreads();

  // ---- GEMM2 (two 64-col halves): y[32x512] = t3 @ lin2_W^T (K=256) + bias + x ----
  #pragma unroll
  for (int h=0; h<2; ++h){
    f32x4 acc2[2][4];
    #pragma unroll
    for (int i=0;i<2;++i)
      #pragma unroll
      for (int j=0;j<4;++j) acc2[i][j] = f32x4{0.f,0.f,0.f,0.f};
    for (int kk=0;kk<8;++kk){
      bf16x8 a[2];
      #pragma unroll
      for (int mt=0;mt<2;++mt){
        const int row = mt*16+lr;
        a[mt] = ld8(&t3[(row*256 + kk*32 + lh*8) ^ ((row&7)<<3)]);
      }
      #pragma unroll
      for (int nt=0;nt<4;++nt){
        bf16x8 bb = ld8(W2f + (size_t)(((w*8 + h*4 + nt)*8) + kk)*512 + l*8);
        #pragma unroll
        for (int mt=0;mt<2;++mt) acc2[mt][nt] = mfma16(a[mt], bb, acc2[mt][nt]);
      }
    }
    #pragma unroll
    for (int nt=0;nt<4;++nt){
      const int c2 = w*128 + h*64 + nt*16 + lr;
      const float bias = bl2[c2];
      #pragma unroll
      for (int mt=0;mt<2;++mt){
        #pragma unroll
        for (int r=0;r<4;++r){
          const int mg = m0 + mt*16 + lh*4 + r;
          if (mg < Nn){
            const size_t off = ((size_t)b*Nn + mg)*Cn + c2;
            out[off] = acc2[mt][nt][r] + bias + x[off];
          }
        }
      }
    }
  }
}

extern "C" void kernel_launch(void* const* d_in, const int* in_sizes, int n_in,
                              void* d_out, int out_size, void* d_ws, size_t ws_size,
                              hipStream_t stream){
  const float* x    = (const float*)d_in[0];
  const float* adj  = (const float*)d_in[1];
  const float* prw  = (const float*)d_in[2];
  const float* prb  = (const float*)d_in[3];
  const float* W1   = (const float*)d_in[4];
  const float* b1   = (const float*)d_in[5];
  const float* n1w  = (const float*)d_in[6];
  const float* n1b  = (const float*)d_in[7];
  const float* Wc   = (const float*)d_in[8];
  const float* cbv  = (const float*)d_in[9];
  const float* n2w  = (const float*)d_in[10];
  const float* n2b  = (const float*)d_in[11];
  const float* W2   = (const float*)d_in[12];
  const float* bl2  = (const float*)d_in[13];

  u16* ws    = (u16*)d_ws;
  u16* W1f   = ws;                                   // 131072 u16
  u16* WcTf  = ws + 131072;                          // 65536
  u16* W2f   = ws + 131072 + 65536;                  // 131072
  u16* supT  = ws + 327680;                          // 32*16*54*512  = 14,155,776 u16 (~27 MiB)
  u16* adjF  = supT + (size_t)32*16*54*512;          // 32*108*54*512 = 95,551,488 u16 (~182 MiB)

  k_prep<<<dim3(160), dim3(256), 0, stream>>>(W1, Wc, W2, W1f, WcTf, W2f);
  k_stageA<<<dim3(NK,Bn), dim3(256), 0, stream>>>(x, prw, prb, W1f, b1, n1w, n1b, WcTf, supT);
  k_adjT<<<dim3(3456), dim3(256), 0, stream>>>(adj, adjF);
  k_stageB<<<dim3(1728), dim3(256), 0, stream>>>(adjF, supT, cbv, n2w, n2b, W2f, bl2, x, (float*)d_out);
}